// Round 2
// baseline (281.544 us; speedup 1.0000x reference)
//
#include <hip/hip_runtime.h>
#include <hip/hip_bf16.h>
#include <cstdint>
#include <cstddef>

// JacobiKANLinear: DEGREE=5, A=B=1.0. Inputs fp32, output fp32 (HW-verified r1/r2/r5).
// v3: FUSED A-expansion. Aaug (100 MB) is eliminated; the GEMM computes
// [silu(x), P1..P5(tanh x)] on the fly while staging. K reordered input-major:
// k = i*6 + j, so a BK=96 window = 16 whole inputs. prep shrinks to weights-only.
#define BATCH   8192
#define IN_F    1024
#define OUT_F   1024
#define KAUG    (6 * 1024)   // k = i*6 + j ; j=0 -> base weight (silu), j=1..5 -> P_j
#define NSTEP   64           // K-steps: 6144 / 96

typedef __bf16 bf16x8 __attribute__((ext_vector_type(8)));
typedef float  f32x4  __attribute__((ext_vector_type(4)));

// Workspace layout (bytes), ~12.6 MB:
static constexpr size_t WAUG_B    = (size_t)OUT_F * KAUG * 2;        // 12,582,912
static constexpr size_t BIAS2_OFF = WAUG_B;                          // 4 KB f32
static constexpr size_t MMAP_OFF  = WAUG_B + 4096;
static constexpr size_t NMAP_OFF  = MMAP_OFF + 1024;

// Jacobi recurrence for A=B=1 (beta_n = 0): P_k = (a_k t)P_{k-1} - (b_k)P_{k-2}
__device__ __constant__ float JAC_A[4] = {64.f/120.f, 180.f/336.f, 384.f/720.f, 700.f/1320.f};
__device__ __constant__ float JAC_B[4] = {48.f/120.f, 144.f/336.f, 320.f/720.f, 600.f/1320.f};

__device__ __forceinline__ unsigned short f2bf(float f)
{
    __hip_bfloat16 h = __float2bfloat16(f);
    return *(unsigned short*)&h;
}
__device__ __forceinline__ unsigned pack2(float lo, float hi)
{
    return (unsigned)f2bf(lo) | ((unsigned)f2bf(hi) << 16);
}
__device__ __forceinline__ float fast_tanh(float x)
{
    const float xc = fminf(fmaxf(x, -15.f), 15.f);
    const float e  = __expf(2.f * xc);
    return (e - 1.f) / (e + 1.f);
}

// ---------------- MFMA C/D layout probe (feeds epilogue) ----------------
__global__ void probe_layout(int* __restrict__ mmap, int* __restrict__ nmap)
{
    __shared__ __align__(16) __hip_bfloat16 A1[16 * 32], B1[16 * 32];
    __shared__ __align__(16) __hip_bfloat16 A2[16 * 32], B2[16 * 32];
    const int lane = threadIdx.x;
    for (int e = lane; e < 512; e += 64) {
        const int m = e >> 5, k = e & 31;
        A1[e] = __float2bfloat16((k == 0) ? (float)(m + 1) : 0.f);
        B1[e] = __float2bfloat16((k == 0) ? 1.f : 0.f);
        A2[e] = __float2bfloat16((k == 0) ? 1.f : 0.f);
        B2[e] = __float2bfloat16((k == 0) ? (float)(m + 1) : 0.f);
    }
    __syncthreads();
    const int quad = lane >> 4, mr = lane & 15;
    const int fi = mr * 4 + quad;
    f32x4 z = {};
    f32x4 d1 = __builtin_amdgcn_mfma_f32_16x16x32_bf16(((const bf16x8*)A1)[fi], ((const bf16x8*)B1)[fi], z, 0, 0, 0);
    f32x4 d2 = __builtin_amdgcn_mfma_f32_16x16x32_bf16(((const bf16x8*)A2)[fi], ((const bf16x8*)B2)[fi], z, 0, 0, 0);
#pragma unroll
    for (int r = 0; r < 4; ++r) {
        mmap[lane * 4 + r] = (int)(d1[r] + 0.5f) - 1;
        nmap[lane * 4 + r] = (int)(d2[r] + 0.5f) - 1;
    }
}

// ---------------- prep: weights + bias fold only (1024 blocks) ----------------
// Waug[o][i*6 + 0] = bf16(W[o][i]) ; Waug[o][i*6 + j] = bf16(C[o][i][j]), j=1..5.
// bias2[o] = bias[o] + sum_i C[o][i][0]  (P0 == 1 fold).
__global__ void prep_w(const float* __restrict__ W,
                       const float* __restrict__ C,
                       const float* __restrict__ bias,
                       __hip_bfloat16* __restrict__ Waug,
                       float* __restrict__ bias2)
{
    const int o = blockIdx.x;
    const int tid = threadIdx.x;
    const int i = tid * 4;

    const float4 wv = *(const float4*)(W + (size_t)o * IN_F + i);
    const float w4[4] = {wv.x, wv.y, wv.z, wv.w};

    float f[24];   // 24 consecutive floats = C[o][i..i+3][0..5]
    const float2* cp = (const float2*)(C + ((size_t)o * IN_F + i) * 6);
#pragma unroll
    for (int q = 0; q < 12; ++q) { const float2 v = cp[q]; f[q * 2] = v.x; f[q * 2 + 1] = v.y; }

    unsigned pk[12];
#pragma unroll
    for (int q = 0; q < 4; ++q) {
        pk[q * 3 + 0] = pack2(w4[q],        f[q * 6 + 1]);
        pk[q * 3 + 1] = pack2(f[q * 6 + 2], f[q * 6 + 3]);
        pk[q * 3 + 2] = pack2(f[q * 6 + 4], f[q * 6 + 5]);
    }
    uint4* dst = (uint4*)(Waug + (size_t)o * KAUG + (size_t)tid * 24);  // 48 B/thread, contiguous
    dst[0] = make_uint4(pk[0], pk[1], pk[2],  pk[3]);
    dst[1] = make_uint4(pk[4], pk[5], pk[6],  pk[7]);
    dst[2] = make_uint4(pk[8], pk[9], pk[10], pk[11]);

    float s = f[0] + f[6] + f[12] + f[18];        // j=0 terms
#pragma unroll
    for (int off = 32; off > 0; off >>= 1) s += __shfl_down(s, off, 64);
    __shared__ float red[4];
    if ((tid & 63) == 0) red[tid >> 6] = s;
    __syncthreads();
    if (tid == 0) bias2[o] = bias[o] + red[0] + red[1] + red[2] + red[3];
}

// ---------------- fused GEMM ----------------
// 128x128 tile, BK=96 (16 inputs), 256 threads (2x2 waves, 64x64/wave).
// A: computed on the fly from x (fp32) -> regs -> ds_write bf16 (single buffer).
// B: Waug via global_load_lds, double-buffered, issued at top of compute so the
//    __syncthreads vmcnt drain sees loads aged by a full compute phase (r0-proven).
// LDS: As 24 KB + Bs 2x24 KB = 72 KB -> 2 blocks/CU (cross-block overlap, m114).
// Rows are 192 B (12 x 16B chunks): fragment ds_read_b128 lands 2 lanes/bank
// (free) with NO swizzle (192 B == 16-word bank shift per row spreads quads).
// Grid (M=64 fastest, N=8): XCD = bx%8 -> the 8 N-blocks sharing an x-tile sit
// on one XCD; x is expanded redundantly (x8) but read from L2.
__device__ __forceinline__ void async_load16(const void* g, void* l)
{
    __builtin_amdgcn_global_load_lds(
        (const __attribute__((address_space(1))) void*)g,
        (__attribute__((address_space(3))) void*)l,
        16, 0, 0);
}

#define AS_B    24576                 // As bytes (128 rows x 192 B)
#define BS_B    24576                 // per-buffer Bs bytes
#define SMEM_B  (AS_B + 2 * BS_B)     // 73728

__global__ __launch_bounds__(256, 2)
void gemm_kan(const float* __restrict__ X,
              const __hip_bfloat16* __restrict__ Waug,
              const float* __restrict__ bias2,
              const int* __restrict__ mmap,
              const int* __restrict__ nmap,
              float* __restrict__ out)
{
    extern __shared__ __align__(16) char smem[];   // [As 24576 | Bs0 24576 | Bs1 24576]

    const int tid  = threadIdx.x;
    const int lane = tid & 63;
    const int wave = tid >> 6;
    const int wm = wave & 1, wn = wave >> 1;
    const int mBase = blockIdx.x * 128;            // M fastest -> XCD = bx % 8
    const int nBase = blockIdx.y * 128;

    // ---- x source for expansion: row r = tid>>1, inputs (tid&1)*8 .. +7 ----
    const float* gx = X + (size_t)(mBase + (tid >> 1)) * IN_F + (tid & 1) * 8;
    char* const aw = smem + (tid >> 1) * 192 + (tid & 1) * 96;   // thread's 96 B in As

    // ---- B staging: 6 x 16B chunks per thread; LDS dest wave-uniform base ----
    const __hip_bfloat16* gB[6]; int lB[6];
#pragma unroll
    for (int q = 0; q < 6; ++q) {
        const int ci = (q * 4 + wave) * 64 + lane;   // 16B-chunk index in 24 KB tile
        const int br = ci / 12, bc = ci - br * 12;   // row 0..127, chunk 0..11
        gB[q] = Waug + (size_t)(nBase + br) * KAUG + bc * 8;
        lB[q] = AS_B + (q * 4 + wave) * 1024;        // + lane*16 added by HW
    }

    // ---- fragment offsets (16B-vector units) ----
    const int quad = lane >> 4, mr = lane & 15;
    const int aoff = (wm * 64 + mr) * 12 + quad;
    const int boff = (AS_B / 16) + (wn * 64 + mr) * 12 + quad;

    f32x4 acc[4][4] = {};

    // ---- prologue: x(0) to regs; B-stage(0) -> buf0 ----
    float4 xc0 = *(const float4*)(gx);
    float4 xc1 = *(const float4*)(gx + 4);
#pragma unroll
    for (int q = 0; q < 6; ++q) async_load16(gB[q], smem + lB[q]);

#pragma unroll 1
    for (int t = 0; t < NSTEP; ++t) {
        // ---- expand 8 inputs -> 48 bf16 (regs only; static indexing) ----
        const float xs[8] = {xc0.x, xc0.y, xc0.z, xc0.w, xc1.x, xc1.y, xc1.z, xc1.w};
        unsigned pk[24];
#pragma unroll
        for (int e = 0; e < 8; ++e) {
            const float x  = xs[e];
            const float s  = x / (1.f + __expf(-x));
            const float tt = fast_tanh(x);
            const float p1 = 2.f * tt;
            const float p2 = JAC_A[0] * tt * p1 - JAC_B[0];
            const float p3 = JAC_A[1] * tt * p2 - JAC_B[1] * p1;
            const float p4 = JAC_A[2] * tt * p3 - JAC_B[2] * p2;
            const float p5 = JAC_A[3] * tt * p4 - JAC_B[3] * p3;
            pk[e * 3 + 0] = pack2(s,  p1);
            pk[e * 3 + 1] = pack2(p2, p3);
            pk[e * 3 + 2] = pack2(p4, p5);
        }
        __syncthreads();               // all waves done reading As(t-1); drains aged vmem
        // ---- write As(t) ----
#pragma unroll
        for (int j = 0; j < 6; ++j)
            *(uint4*)(aw + j * 16) = make_uint4(pk[j * 4], pk[j * 4 + 1],
                                                pk[j * 4 + 2], pk[j * 4 + 3]);
        __syncthreads();               // As(t) visible (lgkm drain; no young vmem)

        // ---- issue next-step loads FIRST: they age through the compute phase ----
        if (t + 1 < NSTEP) {
            char* const bs = smem + ((t + 1) & 1) * BS_B;
#pragma unroll
            for (int q = 0; q < 6; ++q) async_load16(gB[q] + (t + 1) * 96, bs + lB[q]);
            xc0 = *(const float4*)(gx + (t + 1) * 16);
            xc1 = *(const float4*)(gx + (t + 1) * 16 + 4);
        }

        // ---- compute: 3 k-chunks x 16 MFMA from As + Bs[t&1] ----
        const bf16x8* V = (const bf16x8*)smem;
        const int bo = boff + (t & 1) * (BS_B / 16);
#pragma unroll
        for (int kc = 0; kc < 3; ++kc) {
            bf16x8 a[4], b[4];
#pragma unroll
            for (int t4 = 0; t4 < 4; ++t4) a[t4] = V[aoff + t4 * 192 + kc * 4];
#pragma unroll
            for (int t4 = 0; t4 < 4; ++t4) b[t4] = V[bo + t4 * 192 + kc * 4];
#pragma unroll
            for (int i = 0; i < 4; ++i)
#pragma unroll
                for (int jj = 0; jj < 4; ++jj)
                    acc[i][jj] = __builtin_amdgcn_mfma_f32_16x16x32_bf16(a[i], b[jj], acc[i][jj], 0, 0, 0);
        }
    }

    // ---- direct-store epilogue via measured C/D maps ----
    const int4 mv = ((const int4*)mmap)[lane];
    const int4 nv = ((const int4*)nmap)[lane];
    const int mm[4] = {mv.x, mv.y, mv.z, mv.w};
    const int nn[4] = {nv.x, nv.y, nv.z, nv.w};
#pragma unroll
    for (int i = 0; i < 4; ++i) {
#pragma unroll
        for (int jj = 0; jj < 4; ++jj) {
#pragma unroll
            for (int r = 0; r < 4; ++r) {
                const int row = mBase + wm * 64 + i * 16 + mm[r];
                const int col = nBase + wn * 64 + jj * 16 + nn[r];
                out[(size_t)row * OUT_F + col] = acc[i][jj][r] + bias2[col];
            }
        }
    }
}

// ---------------- launch ----------------

extern "C" void kernel_launch(void* const* d_in, const int* in_sizes, int n_in,
                              void* d_out, int out_size, void* d_ws, size_t ws_size,
                              hipStream_t stream)
{
    (void)out_size; (void)ws_size;
    const float* x    = (const float*)d_in[0];
    const float* W    = (const float*)d_in[1];
    const float* C    = (const float*)d_in[2];
    const float* bias = (const float*)d_in[3];
    for (int i = 0; i < n_in; ++i) {
        if      (in_sizes[i] == BATCH * IN_F)     x    = (const float*)d_in[i];
        else if (in_sizes[i] == OUT_F * IN_F)     W    = (const float*)d_in[i];
        else if (in_sizes[i] == OUT_F * IN_F * 6) C    = (const float*)d_in[i];
        else if (in_sizes[i] == OUT_F)            bias = (const float*)d_in[i];
    }
    float* out = (float*)d_out;
    char* ws = (char*)d_ws;
    __hip_bfloat16* Waug  = (__hip_bfloat16*)ws;
    float*          bias2 = (float*)(ws + BIAS2_OFF);
    int*            mmap  = (int*)(ws + MMAP_OFF);
    int*            nmap  = (int*)(ws + NMAP_OFF);

    // 72 KB dynamic LDS (> 64 KB default): opt in once (proven path, r1).
    static bool smem_attr_done = false;
    if (!smem_attr_done) {
        (void)hipFuncSetAttribute((const void*)gemm_kan,
                                  hipFuncAttributeMaxDynamicSharedMemorySize,
                                  SMEM_B);
        smem_attr_done = true;
    }

    probe_layout<<<dim3(1), dim3(64), 0, stream>>>(mmap, nmap);
    prep_w<<<dim3(OUT_F), dim3(256), 0, stream>>>(W, C, bias, Waug, bias2);
    gemm_kan<<<dim3(BATCH / 128, OUT_F / 128), dim3(256), SMEM_B, stream>>>(
        x, Waug, bias2, mmap, nmap, out);
}

// Round 3
// 222.822 us; speedup vs baseline: 1.2635x; 1.2635x over previous
//
#include <hip/hip_runtime.h>
#include <hip/hip_bf16.h>
#include <cstdint>
#include <cstddef>

// JacobiKANLinear: DEGREE=5, A=B=1.0. Inputs fp32, output fp32 (HW-verified r1/r2/r5).
// v4: fused A-expansion (v3 structure) with the VALU cost slashed:
//   - silu/tanh via v_rcp_f32 (no precise-div sequences)
//   - bf16 packing via v_cvt_pk_bf16_f32 (1 instr per 2 values, was ~16)
//   - epilogue C/D map hardcoded (m89-verified: row=quad*4+r, col=mr); probe dropped
#define BATCH   8192
#define IN_F    1024
#define OUT_F   1024
#define KAUG    (6 * 1024)   // k = i*6 + j ; j=0 -> base weight (silu), j=1..5 -> P_j
#define NSTEP   64           // K-steps: 6144 / 96

typedef __bf16 bf16x8 __attribute__((ext_vector_type(8)));
typedef float  f32x4  __attribute__((ext_vector_type(4)));

// Workspace layout (bytes), ~12.6 MB:
static constexpr size_t WAUG_B    = (size_t)OUT_F * KAUG * 2;        // 12,582,912
static constexpr size_t BIAS2_OFF = WAUG_B;                          // 4 KB f32

// Jacobi recurrence for A=B=1 (beta_n = 0): P_k = (a_k t)P_{k-1} - (b_k)P_{k-2}
// constexpr so the unrolled recurrence folds them to inline literals (no s_load).
constexpr float JA[4] = {64.f/120.f, 180.f/336.f, 384.f/720.f, 700.f/1320.f};
constexpr float JB[4] = {48.f/120.f, 144.f/336.f, 320.f/720.f, 600.f/1320.f};

__device__ __forceinline__ unsigned short f2bf(float f)
{
    __hip_bfloat16 h = __float2bfloat16(f);
    return *(unsigned short*)&h;
}
__device__ __forceinline__ unsigned pack2(float lo, float hi)   // RNE (prep path)
{
    return (unsigned)f2bf(lo) | ((unsigned)f2bf(hi) << 16);
}
// Fast packed conversion for the hot expansion path: D[15:0]=bf16(lo), D[31:16]=bf16(hi).
__device__ __forceinline__ unsigned cvt_pk(float lo, float hi)
{
    unsigned r;
    asm("v_cvt_pk_bf16_f32 %0, %1, %2" : "=v"(r) : "v"(lo), "v"(hi));
    return r;
}

// ---------------- prep: weights + bias fold only (1024 blocks) ----------------
// Waug[o][i*6 + 0] = bf16(W[o][i]) ; Waug[o][i*6 + j] = bf16(C[o][i][j]), j=1..5.
// bias2[o] = bias[o] + sum_i C[o][i][0]  (P0 == 1 fold).
__global__ void prep_w(const float* __restrict__ W,
                       const float* __restrict__ C,
                       const float* __restrict__ bias,
                       __hip_bfloat16* __restrict__ Waug,
                       float* __restrict__ bias2)
{
    const int o = blockIdx.x;
    const int tid = threadIdx.x;
    const int i = tid * 4;

    const float4 wv = *(const float4*)(W + (size_t)o * IN_F + i);
    const float w4[4] = {wv.x, wv.y, wv.z, wv.w};

    float f[24];   // 24 consecutive floats = C[o][i..i+3][0..5]
    const float2* cp = (const float2*)(C + ((size_t)o * IN_F + i) * 6);
#pragma unroll
    for (int q = 0; q < 12; ++q) { const float2 v = cp[q]; f[q * 2] = v.x; f[q * 2 + 1] = v.y; }

    unsigned pk[12];
#pragma unroll
    for (int q = 0; q < 4; ++q) {
        pk[q * 3 + 0] = pack2(w4[q],        f[q * 6 + 1]);
        pk[q * 3 + 1] = pack2(f[q * 6 + 2], f[q * 6 + 3]);
        pk[q * 3 + 2] = pack2(f[q * 6 + 4], f[q * 6 + 5]);
    }
    uint4* dst = (uint4*)(Waug + (size_t)o * KAUG + (size_t)tid * 24);  // 48 B/thread, contiguous
    dst[0] = make_uint4(pk[0], pk[1], pk[2],  pk[3]);
    dst[1] = make_uint4(pk[4], pk[5], pk[6],  pk[7]);
    dst[2] = make_uint4(pk[8], pk[9], pk[10], pk[11]);

    float s = f[0] + f[6] + f[12] + f[18];        // j=0 terms
#pragma unroll
    for (int off = 32; off > 0; off >>= 1) s += __shfl_down(s, off, 64);
    __shared__ float red[4];
    if ((tid & 63) == 0) red[tid >> 6] = s;
    __syncthreads();
    if (tid == 0) bias2[o] = bias[o] + red[0] + red[1] + red[2] + red[3];
}

// ---------------- fused GEMM ----------------
// 128x128 tile, BK=96 (16 inputs), 256 threads (2x2 waves, 64x64/wave).
// A: computed on the fly from x (fp32) -> regs -> ds_write bf16 (single buffer).
// B: Waug via global_load_lds, double-buffered, issued at top of compute so the
//    __syncthreads vmcnt drain sees loads aged by a full compute phase (r0-proven).
// LDS: As 24 KB + Bs 2x24 KB = 72 KB -> 2 blocks/CU (cross-block overlap, m114).
// Fragment ds_read_b128 covers all 8 addr-mod-128 slots uniformly (8-phase floor,
// re-derived r2 post-mortem) -> no read swizzle needed. Write-side 2x phases on
// the 6 ds_write_b128/step cost ~1-2 us: accepted.
// Grid (M=64 fastest, N=8): XCD = bx%8 -> the 8 N-blocks sharing an x-tile sit
// on one XCD; x is expanded redundantly (x8) but read from L2, and the expansion
// VALU (~27 lane-ops/elem after this round's rewrite) hides under MFMA drain.
__device__ __forceinline__ void async_load16(const void* g, void* l)
{
    __builtin_amdgcn_global_load_lds(
        (const __attribute__((address_space(1))) void*)g,
        (__attribute__((address_space(3))) void*)l,
        16, 0, 0);
}

#define AS_B    24576                 // As bytes (128 rows x 192 B)
#define BS_B    24576                 // per-buffer Bs bytes
#define SMEM_B  (AS_B + 2 * BS_B)     // 73728

__global__ __launch_bounds__(256, 2)
void gemm_kan(const float* __restrict__ X,
              const __hip_bfloat16* __restrict__ Waug,
              const float* __restrict__ bias2,
              float* __restrict__ out)
{
    extern __shared__ __align__(16) char smem[];   // [As 24576 | Bs0 24576 | Bs1 24576]

    const int tid  = threadIdx.x;
    const int lane = tid & 63;
    const int wave = tid >> 6;
    const int wm = wave & 1, wn = wave >> 1;
    const int mBase = blockIdx.x * 128;            // M fastest -> XCD = bx % 8
    const int nBase = blockIdx.y * 128;

    // ---- x source for expansion: row r = tid>>1, inputs (tid&1)*8 .. +7 ----
    const float* gx = X + (size_t)(mBase + (tid >> 1)) * IN_F + (tid & 1) * 8;
    char* const aw = smem + (tid >> 1) * 192 + (tid & 1) * 96;   // thread's 96 B in As

    // ---- B staging: 6 x 16B chunks per thread; LDS dest wave-uniform base ----
    const __hip_bfloat16* gB[6]; int lB[6];
#pragma unroll
    for (int q = 0; q < 6; ++q) {
        const int ci = (q * 4 + wave) * 64 + lane;   // 16B-chunk index in 24 KB tile
        const int br = ci / 12, bc = ci - br * 12;   // row 0..127, chunk 0..11
        gB[q] = Waug + (size_t)(nBase + br) * KAUG + bc * 8;
        lB[q] = AS_B + (q * 4 + wave) * 1024;        // + lane*16 added by HW
    }

    // ---- fragment offsets (16B-vector units) ----
    const int quad = lane >> 4, mr = lane & 15;
    const int aoff = (wm * 64 + mr) * 12 + quad;
    const int boff = (AS_B / 16) + (wn * 64 + mr) * 12 + quad;

    f32x4 acc[4][4] = {};

    // ---- prologue: x(0) to regs; B-stage(0) -> buf0 ----
    float4 xc0 = *(const float4*)(gx);
    float4 xc1 = *(const float4*)(gx + 4);
#pragma unroll
    for (int q = 0; q < 6; ++q) async_load16(gB[q], smem + lB[q]);

#pragma unroll 1
    for (int t = 0; t < NSTEP; ++t) {
        // ---- expand 8 inputs -> 48 bf16 (regs only; ~27 lane-ops/elem) ----
        const float xs[8] = {xc0.x, xc0.y, xc0.z, xc0.w, xc1.x, xc1.y, xc1.z, xc1.w};
        unsigned pk[24];
#pragma unroll
        for (int e = 0; e < 8; ++e) {
            const float x  = xs[e];
            // v = e^-x, clamped so u = v*v stays finite (x <= -43: sig->0, t->-1)
            const float v  = __expf(fminf(-x, 43.f));
            const float sg = __builtin_amdgcn_rcpf(1.f + v);
            const float s  = x * sg;                  // silu(x) = x * sigmoid(x)
            const float u  = v * v;                   // e^-2x
            const float tt = (1.f - u) * __builtin_amdgcn_rcpf(1.f + u);   // tanh(x)
            const float p1 = 2.f * tt;
            const float p2 = JA[0] * tt * p1 - JB[0];
            const float p3 = JA[1] * tt * p2 - JB[1] * p1;
            const float p4 = JA[2] * tt * p3 - JB[2] * p2;
            const float p5 = JA[3] * tt * p4 - JB[3] * p3;
            pk[e * 3 + 0] = cvt_pk(s,  p1);
            pk[e * 3 + 1] = cvt_pk(p2, p3);
            pk[e * 3 + 2] = cvt_pk(p4, p5);
        }
        __syncthreads();               // all waves done reading As(t-1); drains aged vmem
        // ---- write As(t) ----
#pragma unroll
        for (int j = 0; j < 6; ++j)
            *(uint4*)(aw + j * 16) = make_uint4(pk[j * 4], pk[j * 4 + 1],
                                                pk[j * 4 + 2], pk[j * 4 + 3]);
        __syncthreads();               // As(t) visible (lgkm drain; no young vmem)

        // ---- issue next-step loads FIRST: they age through the compute phase ----
        if (t + 1 < NSTEP) {
            char* const bs = smem + ((t + 1) & 1) * BS_B;
#pragma unroll
            for (int q = 0; q < 6; ++q) async_load16(gB[q] + (t + 1) * 96, bs + lB[q]);
            xc0 = *(const float4*)(gx + (t + 1) * 16);
            xc1 = *(const float4*)(gx + (t + 1) * 16 + 4);
        }

        // ---- compute: 3 k-chunks x 16 MFMA from As + Bs[t&1] ----
        const bf16x8* V = (const bf16x8*)smem;
        const int bo = boff + (t & 1) * (BS_B / 16);
#pragma unroll
        for (int kc = 0; kc < 3; ++kc) {
            bf16x8 a[4], b[4];
#pragma unroll
            for (int t4 = 0; t4 < 4; ++t4) a[t4] = V[aoff + t4 * 192 + kc * 4];
#pragma unroll
            for (int t4 = 0; t4 < 4; ++t4) b[t4] = V[bo + t4 * 192 + kc * 4];
#pragma unroll
            for (int i = 0; i < 4; ++i)
#pragma unroll
                for (int jj = 0; jj < 4; ++jj)
                    acc[i][jj] = __builtin_amdgcn_mfma_f32_16x16x32_bf16(a[i], b[jj], acc[i][jj], 0, 0, 0);
        }
    }

    // ---- direct-store epilogue; C/D map hardcoded (m89-verified, matches the
    // probe this session has measured every run: row_in_16 = quad*4+r, col = mr) ----
#pragma unroll
    for (int i = 0; i < 4; ++i) {
#pragma unroll
        for (int jj = 0; jj < 4; ++jj) {
            const int col = nBase + wn * 64 + jj * 16 + mr;
            const float b2 = bias2[col];
#pragma unroll
            for (int r = 0; r < 4; ++r) {
                const int row = mBase + wm * 64 + i * 16 + quad * 4 + r;
                out[(size_t)row * OUT_F + col] = acc[i][jj][r] + b2;
            }
        }
    }
}

// ---------------- launch ----------------

extern "C" void kernel_launch(void* const* d_in, const int* in_sizes, int n_in,
                              void* d_out, int out_size, void* d_ws, size_t ws_size,
                              hipStream_t stream)
{
    (void)out_size; (void)ws_size;
    const float* x    = (const float*)d_in[0];
    const float* W    = (const float*)d_in[1];
    const float* C    = (const float*)d_in[2];
    const float* bias = (const float*)d_in[3];
    for (int i = 0; i < n_in; ++i) {
        if      (in_sizes[i] == BATCH * IN_F)     x    = (const float*)d_in[i];
        else if (in_sizes[i] == OUT_F * IN_F)     W    = (const float*)d_in[i];
        else if (in_sizes[i] == OUT_F * IN_F * 6) C    = (const float*)d_in[i];
        else if (in_sizes[i] == OUT_F)            bias = (const float*)d_in[i];
    }
    float* out = (float*)d_out;
    char* ws = (char*)d_ws;
    __hip_bfloat16* Waug  = (__hip_bfloat16*)ws;
    float*          bias2 = (float*)(ws + BIAS2_OFF);

    // 72 KB dynamic LDS (> 64 KB default): opt in once (proven path, r1).
    static bool smem_attr_done = false;
    if (!smem_attr_done) {
        (void)hipFuncSetAttribute((const void*)gemm_kan,
                                  hipFuncAttributeMaxDynamicSharedMemorySize,
                                  SMEM_B);
        smem_attr_done = true;
    }

    prep_w<<<dim3(OUT_F), dim3(256), 0, stream>>>(W, C, bias, Waug, bias2);
    gemm_kan<<<dim3(BATCH / 128, OUT_F / 128), dim3(256), SMEM_B, stream>>>(
        x, Waug, bias2, out);
}